// Round 9
// baseline (118.790 us; speedup 1.0000x reference)
//
#include <hip/hip_runtime.h>
#include <hip/hip_bf16.h>

// B=16,S=4096,H=512 ; G=2,V=320,D=256 (Dg=128)
constexpr int BT = 65536;
constexpr int K  = 512;
constexpr int V  = 320;
constexpr int G  = 2;
constexpr int Dg = 128;
constexpr int MT = 64;           // rows per block; 4 waves = 4 col-quarters
constexpr int NSTEP = 16;        // K/32
constexpr size_t WS_IMG = 4096;  // ws: [0,2560) hist ; fragment-ordered B img @4096 (640 KB)

using short8 = __attribute__((ext_vector_type(8))) short;
using f32x4  = __attribute__((ext_vector_type(4))) float;

static __device__ __forceinline__ unsigned short f2bf(float x) {
    unsigned u = __float_as_uint(x);
    unsigned r = 0x7FFFu + ((u >> 16) & 1u);   // RNE
    return (unsigned short)((u + r) >> 16);
}
static __device__ __forceinline__ unsigned pk2(float a, float b) {
    return (unsigned)f2bf(a) | ((unsigned)f2bf(b) << 16);
}
static __device__ __forceinline__ f32x4 mfma16(short8 a, short8 b, f32x4 c) {
    return __builtin_amdgcn_mfma_f32_16x16x32_bf16(a, b, c, 0, 0, 0);
}

// ---- prep: fragment-ordered bf16 B image (R6 layout) ----
// chunk index = (((g*16+t)*4+wc)*5+nt)*64+lane, 16 B each =
// bf16 of W[t*32+(lane>>4)*8 .. +7][g*320 + wc*80+nt*16+(lane&15)]
__global__ __launch_bounds__(256) void vq_prep(const float* __restrict__ Wm,
                                               unsigned char* __restrict__ img)
{
    int id   = blockIdx.x * 256 + threadIdx.x;   // 0..40959
    int lane = id & 63;
    int s    = id >> 6;
    int nt   = s % 5;
    int wcq  = (s / 5) & 3;
    int tk   = s / 20;         // g*16+t
    int g    = tk >> 4;
    int t    = tk & 15;
    int col  = g * V + wcq * 80 + nt * 16 + (lane & 15);
    int kb   = t * 32 + (lane >> 4) * 8;
    unsigned p[4];
#pragma unroll
    for (int jj = 0; jj < 4; ++jj)
        p[jj] = pk2(Wm[(size_t)(kb + 2 * jj) * 640 + col],
                    Wm[(size_t)(kb + 2 * jj + 1) * 640 + col]);
    *reinterpret_cast<uint4*>(img + (size_t)id * 16) = make_uint4(p[0], p[1], p[2], p[3]);
}

// One k-step. At entry: BCUR = B(T) in regs, ACUR = A(T+1) floats in regs,
// LDS buf[T&1] holds A(T). Issues B(T+1)->BNXT and A(T+2)->ANXT, pinned
// before the MFMA region by sched_barrier so they cannot be sunk.
#define STEP(T, BCUR, BNXT, ACURx, ACURy, ANXTx, ANXTy)                          \
    {                                                                            \
        if ((T) + 1 < NSTEP) {                                                   \
            _Pragma("unroll")                                                    \
            for (int nt = 0; nt < 5; ++nt)                                       \
                BNXT[nt] = *reinterpret_cast<const short8*>(                     \
                    bsrc + (size_t)((T) + 1) * 20480 + nt * 1024);               \
        }                                                                        \
        if ((T) + 2 < NSTEP) {                                                   \
            ANXTx = *reinterpret_cast<const float4*>(aptr + ((T) + 2) * 32);     \
            ANXTy = *reinterpret_cast<const float4*>(aptr + ((T) + 2) * 32 + 4); \
        }                                                                        \
        __builtin_amdgcn_sched_barrier(0);                                       \
        short8 av[4];                                                            \
        _Pragma("unroll")                                                        \
        for (int mt = 0; mt < 4; ++mt)                                           \
            av[mt] = *reinterpret_cast<const short8*>(                           \
                &smem[(((T) & 1) ? 4096 : 0) + a_base + mt * 1024]);             \
        _Pragma("unroll")                                                        \
        for (int nt = 0; nt < 5; ++nt)                                           \
            _Pragma("unroll")                                                    \
            for (int mt = 0; mt < 4; ++mt)                                       \
                acc[mt][nt] = mfma16(av[mt], BCUR[nt], acc[mt][nt]);             \
        if ((T) + 1 < NSTEP) packA(ACURx, ACURy, (((T) + 1) & 1) ? 4096 : 0);    \
        asm volatile("s_waitcnt lgkmcnt(0)" ::: "memory");                       \
        __builtin_amdgcn_sched_barrier(0);                                       \
        __builtin_amdgcn_s_barrier();                                            \
    }

// ---- main: bf16 MFMA GEMM (64x320x512), B reg-prefetched, A via 8KB LDS dbuf ----
// grid 2048: g=(bid>>3)&1, rblk=(bid&7)|((bid>>4)<<3) (bid,bid+8 same XCD share hs)
// launch_bounds(256,1): lift the VGPR target so the ~175-reg pipeline stays
// register-resident — R6/R8 showed the default heuristic (88-92 VGPR) sinks the
// B prefetch next to its consumers, exposing a full L2 round-trip per step.
__global__ __launch_bounds__(256, 1) void vq_main(
    const float* __restrict__ hs, const unsigned char* __restrict__ img,
    const float* __restrict__ bv, const float* __restrict__ cbv,
    float* __restrict__ out, unsigned int* __restrict__ hist)
{
    __shared__ __align__(16) unsigned char smem[8192];   // A: [2][64 rows][32 k] bf16, swizzled

    const int tid  = threadIdx.x;
    const int bid  = blockIdx.x;
    const int g    = (bid >> 3) & 1;
    const int rblk = (bid & 7) | ((bid >> 4) << 3);
    const int r0   = rblk * MT;
    const int wc   = tid >> 6;      // wave = col quarter
    const int lane = tid & 63;
    const int l4   = lane & 15;
    const int lc   = lane >> 4;

    f32x4 acc[4][5] = {};

    // A LDS addressing (R8-verified swizzle, conflict-free)
    const int arow = tid >> 2, akq = tid & 3;
    const float* aptr = hs + (size_t)(r0 + arow) * K + akq * 8;
    const int awoff  = (arow * 64 + akq * 16) ^ (((arow >> 1) & 3) << 4);
    const int a_base = (l4 * 64 + lc * 16) ^ (((l4 >> 1) & 3) << 4);
    // B fragment source for this (g,wc,lane)
    const unsigned char* bsrc = img + (size_t)g * 327680 + wc * 5120 + (size_t)lane * 16;

    auto packA = [&](float4 x, float4 y, int boff) {
        *reinterpret_cast<uint4*>(&smem[boff + awoff]) =
            make_uint4(pk2(x.x, x.y), pk2(x.z, x.w), pk2(y.x, y.y), pk2(y.z, y.w));
    };

    short8 bA[5], bB[5];
    float4 aAx, aAy, aBx, aBy;

    // ---- prologue: queue order = [A(0), B(0), A(1)] so packA's auto-wait
    // (consumes A(0), oldest) keeps B(0)/A(1) in flight ----
    float4 a0x = *reinterpret_cast<const float4*>(aptr);
    float4 a0y = *reinterpret_cast<const float4*>(aptr + 4);
#pragma unroll
    for (int nt = 0; nt < 5; ++nt)
        bA[nt] = *reinterpret_cast<const short8*>(bsrc + nt * 1024);
    aAx = *reinterpret_cast<const float4*>(aptr + 32);
    aAy = *reinterpret_cast<const float4*>(aptr + 36);
    __builtin_amdgcn_sched_barrier(0);
    packA(a0x, a0y, 0);
    asm volatile("s_waitcnt lgkmcnt(0)" ::: "memory");
    __builtin_amdgcn_sched_barrier(0);
    __builtin_amdgcn_s_barrier();

    for (int t = 0; t < NSTEP; t += 2) {
        STEP(t,     bA, bB, aAx, aAy, aBx, aBy);
        STEP(t + 1, bB, bA, aBx, aBy, aAx, aAy);
    }

    // ---- epilogue: bias + argmax (D: col=l4, row=lc*4+reg within 16x16 tile) ----
    float biasv[5];
#pragma unroll
    for (int nt = 0; nt < 5; ++nt) biasv[nt] = bv[g * V + wc * 80 + nt * 16 + l4];

    float* red_v = reinterpret_cast<float*>(smem);          // [64][4]  (buf0: dead now)
    int*   red_i = reinterpret_cast<int*>(smem + 1024);     // [64][4]
    int*   idx_s = reinterpret_cast<int*>(smem + 2048);     // [64]

#pragma unroll
    for (int mt = 0; mt < 4; ++mt) {
#pragma unroll
        for (int reg = 0; reg < 4; ++reg) {
            float bestv = acc[mt][0][reg] + biasv[0];
            int   besti = wc * 80 + l4;
#pragma unroll
            for (int nt = 1; nt < 5; ++nt) {
                float v = acc[mt][nt][reg] + biasv[nt];
                int   ci = wc * 80 + nt * 16 + l4;
                if (v > bestv) { bestv = v; besti = ci; }
            }
#pragma unroll
            for (int m = 1; m < 16; m <<= 1) {
                float ov = __shfl_xor(bestv, m);
                int   oi = __shfl_xor(besti, m);
                if (ov > bestv || (ov == bestv && oi < besti)) { bestv = ov; besti = oi; }
            }
            if (l4 == 0) {
                int row = mt * 16 + lc * 4 + reg;
                red_v[row * 4 + wc] = bestv;
                red_i[row * 4 + wc] = besti;
            }
        }
    }
    __syncthreads();

    if (tid < MT) {
        float bb = red_v[tid * 4]; int bi = red_i[tid * 4];
#pragma unroll
        for (int c = 1; c < 4; ++c) {
            float v = red_v[tid * 4 + c]; int ii = red_i[tid * 4 + c];
            if (v > bb || (v == bb && ii < bi)) { bb = v; bi = ii; }
        }
        idx_s[tid] = bi;
        atomicAdd(&hist[g * V + bi], 1u);
    }
    __syncthreads();

    // ---- gather: 64 rows x 32 float4, 8 per thread ----
#pragma unroll
    for (int i = 0; i < 8; ++i) {
        int idx = i * 256 + tid;
        int row = idx >> 5;
        int d4  = idx & 31;
        int vi  = idx_s[row];
        float4 val = *reinterpret_cast<const float4*>(&cbv[((size_t)(g * V + vi)) * Dg + d4 * 4]);
        *reinterpret_cast<float4*>(&out[((size_t)(r0 + row)) * (G * Dg) + g * Dg + d4 * 4]) = val;
    }
}

// Perplexity from histogram: one wave.
__global__ void vq_ppl(const unsigned int* __restrict__ hist, float* __restrict__ outp)
{
    int lane = threadIdx.x;  // 64
    float ppl = 0.0f;
    for (int g = 0; g < G; ++g) {
        float local = 0.0f;
        for (int v = lane; v < V; v += 64) {
            float m = (float)hist[g * V + v] * (1.0f / (float)BT);
            local += m * logf(m + 1e-7f);
        }
#pragma unroll
        for (int off = 32; off; off >>= 1) local += __shfl_down(local, off);
        if (lane == 0) ppl += expf(-local);
    }
    if (lane == 0) outp[0] = ppl;
}

extern "C" void kernel_launch(void* const* d_in, const int* in_sizes, int n_in,
                              void* d_out, int out_size, void* d_ws, size_t ws_size,
                              hipStream_t stream)
{
    const float* hs  = (const float*)d_in[0];   // (65536, 512)
    const float* Wm  = (const float*)d_in[1];   // (512, 640)
    const float* bv  = (const float*)d_in[2];   // (640,)
    const float* cbv = (const float*)d_in[3];   // (640, 128)
    float* out = (float*)d_out;                 // 65536*256 floats + 1 float perplexity

    unsigned int*  hist = (unsigned int*)d_ws;
    unsigned char* img  = (unsigned char*)d_ws + WS_IMG;

    hipMemsetAsync(d_ws, 0, G * V * sizeof(unsigned int), stream);
    vq_prep<<<160, 256, 0, stream>>>(Wm, img);
    vq_main<<<2048, 256, 0, stream>>>(hs, img, bv, cbv, out, hist);
    vq_ppl<<<1, 64, 0, stream>>>(hist, out + (size_t)BT * G * Dg);
}

// Round 10
// 114.042 us; speedup vs baseline: 1.0416x; 1.0416x over previous
//
#include <hip/hip_runtime.h>
#include <hip/hip_bf16.h>

// B=16,S=4096,H=512 ; G=2,V=320,D=256 (Dg=128)
constexpr int BT = 65536;
constexpr int K  = 512;
constexpr int V  = 320;
constexpr int G  = 2;
constexpr int Dg = 128;
constexpr int MT = 64;           // rows per block; 4 waves = 4 col-quarters
constexpr int NSTEP = 16;        // K/32
constexpr size_t WS_IMG = 4096;  // ws: [0,2560) hist ; fragment-ordered B img @4096 (640 KB)

using short8 = __attribute__((ext_vector_type(8))) short;
using f32x4  = __attribute__((ext_vector_type(4))) float;

static __device__ __forceinline__ unsigned short f2bf(float x) {
    unsigned u = __float_as_uint(x);
    unsigned r = 0x7FFFu + ((u >> 16) & 1u);   // RNE
    return (unsigned short)((u + r) >> 16);
}
static __device__ __forceinline__ unsigned pk2(float a, float b) {
    return (unsigned)f2bf(a) | ((unsigned)f2bf(b) << 16);
}
static __device__ __forceinline__ f32x4 mfma16(short8 a, short8 b, f32x4 c) {
    return __builtin_amdgcn_mfma_f32_16x16x32_bf16(a, b, c, 0, 0, 0);
}

// ---- prep: fragment-ordered bf16 B image (R6 layout, unchanged) ----
// chunk index = (((g*16+t)*4+wc)*5+nt)*64+lane, 16 B each =
// bf16 of W[t*32+(lane>>4)*8 .. +7][g*320 + wc*80+nt*16+(lane&15)]
__global__ __launch_bounds__(256) void vq_prep(const float* __restrict__ Wm,
                                               unsigned char* __restrict__ img)
{
    int id   = blockIdx.x * 256 + threadIdx.x;   // 0..40959
    int lane = id & 63;
    int s    = id >> 6;
    int nt   = s % 5;
    int wcq  = (s / 5) & 3;
    int tk   = s / 20;         // g*16+t
    int g    = tk >> 4;
    int t    = tk & 15;
    int col  = g * V + wcq * 80 + nt * 16 + (lane & 15);
    int kb   = t * 32 + (lane >> 4) * 8;
    unsigned p[4];
#pragma unroll
    for (int jj = 0; jj < 4; ++jj)
        p[jj] = pk2(Wm[(size_t)(kb + 2 * jj) * 640 + col],
                    Wm[(size_t)(kb + 2 * jj + 1) * 640 + col]);
    *reinterpret_cast<uint4*>(img + (size_t)id * 16) = make_uint4(p[0], p[1], p[2], p[3]);
}

// ---- main: bf16 MFMA GEMM (64x320x512), simple 2-barrier structure (R4-proven),
// single 24KB LDS buffer, B via global_load_lds, A reg-staged issue-early.
// grid 2048: g=(bid>>3)&1, rblk=(bid&7)|((bid>>4)<<3) (bid,bid+8 same XCD share hs).
// No launch_bounds min-occupancy arg (R2/R7 spill lesson); no asm pipeline
// (R6/R8/R9: compiler sinks reg prefetch; rely on 16 waves/CU TLP per m114).
__global__ __launch_bounds__(256) void vq_main(
    const float* __restrict__ hs, const unsigned char* __restrict__ img,
    const float* __restrict__ bv, const float* __restrict__ cbv,
    float* __restrict__ out, unsigned int* __restrict__ hist)
{
    __shared__ __align__(16) unsigned char smem[24576];  // A [0,4K) swizzled ; B [4K,24K) frag-ordered

    const int tid  = threadIdx.x;
    const int bid  = blockIdx.x;
    const int g    = (bid >> 3) & 1;
    const int rblk = (bid & 7) | ((bid >> 4) << 3);
    const int r0   = rblk * MT;
    const int wc   = tid >> 6;      // wave = col quarter
    const int lane = tid & 63;
    const int l4   = lane & 15;
    const int lc   = lane >> 4;

    f32x4 acc[4][5] = {};

    // A staging/read addressing (R8-verified conflict-free swizzle)
    const int arow = tid >> 2, akq = tid & 3;
    const float* aptr = hs + (size_t)(r0 + arow) * K + akq * 8;
    const int awoff  = (arow * 64 + akq * 16) ^ (((arow >> 1) & 3) << 4);
    const int a_base = (l4 * 64 + lc * 16) ^ (((l4 >> 1) & 3) << 4);
    // B: wave w stages and reads its own 5 KB quarter; linear on both sides
    const unsigned char* bsrc = img + (size_t)g * 327680 + wc * 5120 + (size_t)lane * 16;
    const int b_lds = 4096 + wc * 5120;   // + nt*1024 (+ lane*16 on read)

    auto packA = [&](float4 x, float4 y) {
        *reinterpret_cast<uint4*>(&smem[awoff]) =
            make_uint4(pk2(x.x, x.y), pk2(x.z, x.w), pk2(y.x, y.y), pk2(y.z, y.w));
    };

    // prologue: A(0) in flight
    float4 ax = *reinterpret_cast<const float4*>(aptr);
    float4 ay = *reinterpret_cast<const float4*>(aptr + 4);

    for (int t = 0; t < NSTEP; ++t) {
        // ---- stage phase: B(t) via LDS-DMA, A(t) convert+write ----
#pragma unroll
        for (int i = 0; i < 5; ++i)
            __builtin_amdgcn_global_load_lds(
                (const __attribute__((address_space(1))) void*)(bsrc + (size_t)t * 20480 + i * 1024),
                (__attribute__((address_space(3))) void*)(&smem[b_lds + i * 1024]), 16, 0, 0);
        packA(ax, ay);                    // auto-waits A(t) arrival only
        __syncthreads();                  // drains B DMA + LDS writes
        // ---- compute phase; A(t+1) issued first so HBM latency hides under MFMA ----
        if (t + 1 < NSTEP) {
            ax = *reinterpret_cast<const float4*>(aptr + (t + 1) * 32);
            ay = *reinterpret_cast<const float4*>(aptr + (t + 1) * 32 + 4);
        }
        short8 av[4];
#pragma unroll
        for (int mt = 0; mt < 4; ++mt)
            av[mt] = *reinterpret_cast<const short8*>(&smem[a_base + mt * 1024]);
#pragma unroll
        for (int nt = 0; nt < 5; ++nt) {
            short8 bb = *reinterpret_cast<const short8*>(&smem[b_lds + nt * 1024 + lane * 16]);
#pragma unroll
            for (int mt = 0; mt < 4; ++mt) acc[mt][nt] = mfma16(av[mt], bb, acc[mt][nt]);
        }
        __syncthreads();                  // buffer reuse guard
    }

    // ---- epilogue: bias + argmax (D: col=l4, row=lc*4+reg within 16x16 tile) ----
    float biasv[5];
#pragma unroll
    for (int nt = 0; nt < 5; ++nt) biasv[nt] = bv[g * V + wc * 80 + nt * 16 + l4];

    float* red_v = reinterpret_cast<float*>(smem);          // [64][4]
    int*   red_i = reinterpret_cast<int*>(smem + 1024);     // [64][4]
    int*   idx_s = reinterpret_cast<int*>(smem + 2048);     // [64]

#pragma unroll
    for (int mt = 0; mt < 4; ++mt) {
#pragma unroll
        for (int reg = 0; reg < 4; ++reg) {
            float bestv = acc[mt][0][reg] + biasv[0];
            int   besti = wc * 80 + l4;
#pragma unroll
            for (int nt = 1; nt < 5; ++nt) {
                float v = acc[mt][nt][reg] + biasv[nt];
                int   ci = wc * 80 + nt * 16 + l4;
                if (v > bestv) { bestv = v; besti = ci; }
            }
#pragma unroll
            for (int m = 1; m < 16; m <<= 1) {
                float ov = __shfl_xor(bestv, m);
                int   oi = __shfl_xor(besti, m);
                if (ov > bestv || (ov == bestv && oi < besti)) { bestv = ov; besti = oi; }
            }
            if (l4 == 0) {
                int row = mt * 16 + lc * 4 + reg;
                red_v[row * 4 + wc] = bestv;
                red_i[row * 4 + wc] = besti;
            }
        }
    }
    __syncthreads();

    if (tid < MT) {
        float bb = red_v[tid * 4]; int bi = red_i[tid * 4];
#pragma unroll
        for (int c = 1; c < 4; ++c) {
            float v = red_v[tid * 4 + c]; int ii = red_i[tid * 4 + c];
            if (v > bb || (v == bb && ii < bi)) { bb = v; bi = ii; }
        }
        idx_s[tid] = bi;
        atomicAdd(&hist[g * V + bi], 1u);
    }
    __syncthreads();

    // ---- gather: 64 rows x 32 float4, 8 per thread ----
#pragma unroll
    for (int i = 0; i < 8; ++i) {
        int idx = i * 256 + tid;
        int row = idx >> 5;
        int d4  = idx & 31;
        int vi  = idx_s[row];
        float4 val = *reinterpret_cast<const float4*>(&cbv[((size_t)(g * V + vi)) * Dg + d4 * 4]);
        *reinterpret_cast<float4*>(&out[((size_t)(r0 + row)) * (G * Dg) + g * Dg + d4 * 4]) = val;
    }
}

// Perplexity from histogram: one wave.
__global__ void vq_ppl(const unsigned int* __restrict__ hist, float* __restrict__ outp)
{
    int lane = threadIdx.x;  // 64
    float ppl = 0.0f;
    for (int g = 0; g < G; ++g) {
        float local = 0.0f;
        for (int v = lane; v < V; v += 64) {
            float m = (float)hist[g * V + v] * (1.0f / (float)BT);
            local += m * logf(m + 1e-7f);
        }
#pragma unroll
        for (int off = 32; off; off >>= 1) local += __shfl_down(local, off);
        if (lane == 0) ppl += expf(-local);
    }
    if (lane == 0) outp[0] = ppl;
}

extern "C" void kernel_launch(void* const* d_in, const int* in_sizes, int n_in,
                              void* d_out, int out_size, void* d_ws, size_t ws_size,
                              hipStream_t stream)
{
    const float* hs  = (const float*)d_in[0];   // (65536, 512)
    const float* Wm  = (const float*)d_in[1];   // (512, 640)
    const float* bv  = (const float*)d_in[2];   // (640,)
    const float* cbv = (const float*)d_in[3];   // (640, 128)
    float* out = (float*)d_out;                 // 65536*256 floats + 1 float perplexity

    unsigned int*  hist = (unsigned int*)d_ws;
    unsigned char* img  = (unsigned char*)d_ws + WS_IMG;

    hipMemsetAsync(d_ws, 0, G * V * sizeof(unsigned int), stream);
    vq_prep<<<160, 256, 0, stream>>>(Wm, img);
    vq_main<<<2048, 256, 0, stream>>>(hs, img, bv, cbv, out, hist);
    vq_ppl<<<1, 64, 0, stream>>>(hist, out + (size_t)BT * G * Dg);
}